// Round 12
// baseline (171.775 us; speedup 1.0000x reference)
//
#include <hip/hip_runtime.h>
#include <math.h>

typedef short s16x8 __attribute__((ext_vector_type(8)));
typedef float f32x4 __attribute__((ext_vector_type(4)));
typedef float f32x16 __attribute__((ext_vector_type(16)));
typedef unsigned short u16;

#define B_ 2
#define T_ 2048
#define HN_ 16

// ---------------- helpers ----------------
__device__ __forceinline__ u16 f2bf(float f) {
  union { float f; unsigned u; } v; v.f = f;
  unsigned r = v.u + 0x7FFFu + ((v.u >> 16) & 1u);   // RNE (finite inputs)
  return (u16)(r >> 16);
}
__device__ __forceinline__ float bf2f(u16 b) {
  union { unsigned u; float f; } v; v.u = ((unsigned)b) << 16;
  return v.f;
}
__device__ __forceinline__ float softplus_f(float v) {
  return fmaxf(v, 0.f) + __logf(1.f + __expf(-fabsf(v)));
}
__device__ __forceinline__ f32x4 mfma16(s16x8 a, s16x8 b, f32x4 c) {
  return __builtin_amdgcn_mfma_f32_16x16x32_bf16(a, b, c, 0, 0, 0);
}
__device__ __forceinline__ f32x16 mfma32(s16x8 a, s16x8 b, f32x16 c) {
  return __builtin_amdgcn_mfma_f32_32x32x16_bf16(a, b, c, 0, 0, 0);
}
__device__ __forceinline__ void gload16(void* lds, const void* g) {
  __builtin_amdgcn_global_load_lds(
      (const __attribute__((address_space(1))) unsigned int*)g,
      (__attribute__((address_space(3))) unsigned int*)lds, 16, 0, 0);
}
__device__ __forceinline__ unsigned cvtpk(float lo, float hi) {
  unsigned r;
  asm("v_cvt_pk_bf16_f32 %0, %1, %2" : "=v"(r) : "v"(lo), "v"(hi));
  return r;
}

// work list: (qt, c, slot) with 256-key chunks; qt descending (heavy first).
__device__ __constant__ unsigned char QTC[72][3] = {
  {15,0,64},{15,1,65},{15,2,66},{15,3,67},{15,4,68},{15,5,69},{15,6,70},{15,7,71},
  {14,0,56},{14,1,57},{14,2,58},{14,3,59},{14,4,60},{14,5,61},{14,6,62},{14,7,63},
  {13,0,49},{13,1,50},{13,2,51},{13,3,52},{13,4,53},{13,5,54},{13,6,55},
  {12,0,42},{12,1,43},{12,2,44},{12,3,45},{12,4,46},{12,5,47},{12,6,48},
  {11,0,36},{11,1,37},{11,2,38},{11,3,39},{11,4,40},{11,5,41},
  {10,0,30},{10,1,31},{10,2,32},{10,3,33},{10,4,34},{10,5,35},
  {9,0,25},{9,1,26},{9,2,27},{9,3,28},{9,4,29},
  {8,0,20},{8,1,21},{8,2,22},{8,3,23},{8,4,24},
  {7,0,16},{7,1,17},{7,2,18},{7,3,19},
  {6,0,12},{6,1,13},{6,2,14},{6,3,15},
  {5,0,9},{5,1,10},{5,2,11},
  {4,0,6},{4,1,7},{4,2,8},
  {3,0,4},{3,1,5},
  {2,0,2},{2,1,3},
  {1,0,1},
  {0,0,0}
};
__device__ __constant__ unsigned char OFFT[16] =
  {0,1,2,4,6,9,12,16,20,25,30,36,42,49,56,64};

// ---------------- fused prep: conv x / w_attn / w_proj + tables + knmax ----------------
__device__ __forceinline__ void conv_one(
    const float* __restrict__ in, u16* __restrict__ out, int c)
{
  int row = c >> 7, cc = c & 127;           // 128 chunks per 1024-elem row
  int ks = cc >> 3, ch = cc & 7;
  const float4* src = (const float4*)(in + ((size_t)row << 10) + (cc << 3));
  float4 a = src[0], b = src[1];
  s16x8 o;
  o[0] = (short)f2bf(a.x); o[1] = (short)f2bf(a.y);
  o[2] = (short)f2bf(a.z); o[3] = (short)f2bf(a.w);
  o[4] = (short)f2bf(b.x); o[5] = (short)f2bf(b.y);
  o[6] = (short)f2bf(b.z); o[7] = (short)f2bf(b.w);
  *(s16x8*)(out + ((size_t)row << 10) + (ks << 6) + ((ch ^ (row & 7)) << 3)) = o;
}

__global__ __launch_bounds__(256) void prep_all(
    const float* __restrict__ x, const float* __restrict__ w_attn,
    const float* __restrict__ w_proj, const float* __restrict__ delta,
    u16* __restrict__ xb, u16* __restrict__ wab, u16* __restrict__ wpb,
    float* __restrict__ postab, float* __restrict__ dtab, int* __restrict__ knmaxI)
{
  const int gid = blockIdx.x * 256 + threadIdx.x;
  if (gid < 32) knmaxI[gid] = 0;
  if (gid < 524288) {                        // x: 4096*128 chunks
    conv_one(x, xb, gid);
  } else if (gid < 917504) {                 // w_attn: 3072*128
    conv_one(w_attn, wab, gid - 524288);
  } else if (gid < 1048576) {                // w_proj: 1024*128
    conv_one(w_proj, wpb, gid - 917504);
  } else {                                   // tables: T_*64
    int idx = gid - 1048576;
    int t = idx >> 6, d = idx & 63;
    float invf = powf(10000.f, -(float)d * (1.0f / 64.0f));
    float ang = (float)t * invf;
    float sp, cp;
    sincosf(ang, &sp, &cp);
    postab[idx * 2 + 0] = cp;
    postab[idx * 2 + 1] = sp;
    if (idx < HN_ * 64) {
      float dl = delta[idx];
      dl = fminf(fmaxf(dl, -6.2831853071795865f), 0.f);
      float sd, cd;
      sincosf(dl, &sd, &cd);
      dtab[idx * 2 + 0] = cd;
      dtab[idx * 2 + 1] = sd;
    }
  }
}

// ---------------- bf16 MFMA GEMM (NT), 128x128, 4 waves ----------------
template<int OUTK>
__global__ __launch_bounds__(256) void gemm_nt_mfma(
    const u16* __restrict__ A, const u16* __restrict__ Bw,
    void* __restrict__ Cout, int N)
{
  __shared__ u16 As[128 * 64];
  __shared__ u16 Bs[128 * 64];
  const int tid = threadIdx.x;
  const int w = tid >> 6, l = tid & 63, g = l >> 4;
  const int bm = blockIdx.y * 128, bn = blockIdx.x * 128;
  const int wr = w >> 1, wc = w & 1;
  const int K = 1024;

  const f32x4 zero = {0.f, 0.f, 0.f, 0.f};
  f32x4 acc[4][4];
  #pragma unroll
  for (int mt = 0; mt < 4; ++mt)
    #pragma unroll
    for (int nt = 0; nt < 4; ++nt) acc[mt][nt] = zero;

  for (int kt = 0; kt < K; kt += 64) {
    __syncthreads();
    #pragma unroll
    for (int j = 0; j < 4; ++j) {
      int cid = (j * 4 + w) * 64 + l;           // chunk 0..1023
      int row = cid >> 3, cc = cid & 7;
      gload16(As + ((j * 4 + w) << 9), A  + (size_t)(bm + row) * K + kt + cc * 8);
      gload16(Bs + ((j * 4 + w) << 9), Bw + (size_t)(bn + row) * K + kt + cc * 8);
    }
    __syncthreads();
    #pragma unroll
    for (int ks = 0; ks < 2; ++ks) {
      s16x8 af[4], bfr[4];
      #pragma unroll
      for (int mt = 0; mt < 4; ++mt) {
        int rr = wr * 64 + mt * 16 + (l & 15);
        af[mt] = *(const s16x8*)(As + rr * 64 + (((ks * 4 + g) ^ (rr & 7)) << 3));
      }
      #pragma unroll
      for (int nt = 0; nt < 4; ++nt) {
        int rr = wc * 64 + nt * 16 + (l & 15);
        bfr[nt] = *(const s16x8*)(Bs + rr * 64 + (((ks * 4 + g) ^ (rr & 7)) << 3));
      }
      #pragma unroll
      for (int mt = 0; mt < 4; ++mt)
        #pragma unroll
        for (int nt = 0; nt < 4; ++nt)
          acc[mt][nt] = mfma16(af[mt], bfr[nt], acc[mt][nt]);
    }
  }

  #pragma unroll
  for (int mt = 0; mt < 4; ++mt)
    #pragma unroll
    for (int nt = 0; nt < 4; ++nt)
      #pragma unroll
      for (int r = 0; r < 4; ++r) {
        int row = bm + wr * 64 + mt * 16 + g * 4 + r;
        int col = bn + wc * 64 + nt * 16 + (l & 15);
        if (OUTK == 0)
          ((u16*)Cout)[(size_t)row * N + col] = f2bf(acc[mt][nt][r]);
        else
          ((float*)Cout)[(size_t)row * N + col] = acc[mt][nt][r];
      }
}

// ---------------- bf16 MFMA GEMM (NT), 128x256, 8 waves (for qkv) ----------------
__global__ __launch_bounds__(512) void gemm_nt_mfma256(
    const u16* __restrict__ A, const u16* __restrict__ Bw,
    u16* __restrict__ Cout, int N)
{
  __shared__ u16 As[128 * 64];               // 16 KB
  __shared__ u16 Bs[256 * 64];               // 32 KB
  const int tid = threadIdx.x;
  const int w = tid >> 6, l = tid & 63, g = l >> 4;
  const int bm = blockIdx.y * 128, bn = blockIdx.x * 256;
  const int wr = w >> 2, wc = w & 3;         // 2 x 4 waves, 64x64 each
  const int K = 1024;

  const f32x4 zero = {0.f, 0.f, 0.f, 0.f};
  f32x4 acc[4][4];
  #pragma unroll
  for (int mt = 0; mt < 4; ++mt)
    #pragma unroll
    for (int nt = 0; nt < 4; ++nt) acc[mt][nt] = zero;

  for (int kt = 0; kt < K; kt += 64) {
    __syncthreads();
    #pragma unroll
    for (int j = 0; j < 2; ++j) {            // A: 1024 chunks, 16 groups
      int grp = j * 8 + w;
      int cid = grp * 64 + l;
      int row = cid >> 3, cc = cid & 7;
      gload16(As + (grp << 9), A + (size_t)(bm + row) * K + kt + cc * 8);
    }
    #pragma unroll
    for (int j = 0; j < 4; ++j) {            // B: 2048 chunks, 32 groups
      int grp = j * 8 + w;
      int cid = grp * 64 + l;
      int row = cid >> 3, cc = cid & 7;
      gload16(Bs + (grp << 9), Bw + (size_t)(bn + row) * K + kt + cc * 8);
    }
    __syncthreads();
    #pragma unroll
    for (int ks = 0; ks < 2; ++ks) {
      s16x8 af[4], bfr[4];
      #pragma unroll
      for (int mt = 0; mt < 4; ++mt) {
        int rr = wr * 64 + mt * 16 + (l & 15);
        af[mt] = *(const s16x8*)(As + rr * 64 + (((ks * 4 + g) ^ (rr & 7)) << 3));
      }
      #pragma unroll
      for (int nt = 0; nt < 4; ++nt) {
        int rr = wc * 64 + nt * 16 + (l & 15);
        bfr[nt] = *(const s16x8*)(Bs + rr * 64 + (((ks * 4 + g) ^ (rr & 7)) << 3));
      }
      #pragma unroll
      for (int mt = 0; mt < 4; ++mt)
        #pragma unroll
        for (int nt = 0; nt < 4; ++nt)
          acc[mt][nt] = mfma16(af[mt], bfr[nt], acc[mt][nt]);
    }
  }

  #pragma unroll
  for (int mt = 0; mt < 4; ++mt)
    #pragma unroll
    for (int nt = 0; nt < 4; ++nt)
      #pragma unroll
      for (int r = 0; r < 4; ++r) {
        int row = bm + wr * 64 + mt * 16 + g * 4 + r;
        int col = bn + wc * 64 + nt * 16 + (l & 15);
        Cout[(size_t)row * N + col] = f2bf(acc[mt][nt][r]);
      }
}

// ---------------- PoPE prepass ----------------
__global__ __launch_bounds__(256) void pope_prep(
    const u16* __restrict__ qkvb, const float* __restrict__ postab,
    const float* __restrict__ dtab, u16* __restrict__ Kp, u16* __restrict__ Vtp,
    u16* __restrict__ Qp, float* __restrict__ qn, int* __restrict__ knmaxI)
{
  __shared__ u16 Vs[64][72];
  __shared__ float knsh[64];
  const int tb = blockIdx.x, h = blockIdx.y, b = blockIdx.z;
  const int t0 = tb * 64, tid = threadIdx.x;
  const int tl = tid >> 2, j = tid & 3, d0 = j * 16;
  const int t = t0 + tl;
  const size_t bh = (size_t)b * HN_ + h;
  const size_t qrow = (size_t)(b * T_ + t) * 3072 + h * 64;
  const float2* pt = (const float2*)postab + (size_t)t * 64 + d0;

  // ---- K with phases (swizzled) + k-norm ----
  float kss = 0.f;
  {
    s16x8 k0 = *(const s16x8*)(qkvb + qrow + 1024 + d0);
    s16x8 k1 = *(const s16x8*)(qkvb + qrow + 1024 + d0 + 8);
    const float2* dt = (const float2*)dtab + h * 64 + d0;
    s16x8 r0, r1, i0, i1;
    #pragma unroll
    for (int i = 0; i < 8; ++i) {
      float mu = softplus_f(bf2f((u16)k0[i]));
      kss += mu * mu;
      float2 cs = pt[i]; float2 dc = dt[i];
      r0[i] = (short)f2bf(mu * (cs.x * dc.x - cs.y * dc.y));
      i0[i] = (short)f2bf(mu * (cs.y * dc.x + cs.x * dc.y));
    }
    #pragma unroll
    for (int i = 0; i < 8; ++i) {
      float mu = softplus_f(bf2f((u16)k1[i]));
      kss += mu * mu;
      float2 cs = pt[8 + i]; float2 dc = dt[8 + i];
      r1[i] = (short)f2bf(mu * (cs.x * dc.x - cs.y * dc.y));
      i1[i] = (short)f2bf(mu * (cs.y * dc.x + cs.x * dc.y));
    }
    u16* Krow = Kp + (bh * T_ + t) * 128;
    int sw = t & 7;
    int c0 = d0 >> 3;
    *(s16x8*)(Krow + ((c0 ^ sw) << 3))       = r0;
    *(s16x8*)(Krow + (((c0 + 1) ^ sw) << 3)) = r1;
    *(s16x8*)(Krow + (((c0 + 8) ^ sw) << 3)) = i0;
    *(s16x8*)(Krow + (((c0 + 9) ^ sw) << 3)) = i1;
  }
  kss += __shfl_xor(kss, 1);
  kss += __shfl_xor(kss, 2);
  if (j == 0) knsh[tl] = kss;

  // ---- Q with pos phase (plain) + q-norm ----
  float qss = 0.f;
  {
    s16x8 q0 = *(const s16x8*)(qkvb + qrow + d0);
    s16x8 q1 = *(const s16x8*)(qkvb + qrow + d0 + 8);
    s16x8 r0, r1, i0, i1;
    #pragma unroll
    for (int i = 0; i < 8; ++i) {
      float mu = softplus_f(bf2f((u16)q0[i]));
      qss += mu * mu;
      float2 cs = pt[i];
      r0[i] = (short)f2bf(mu * cs.x);
      i0[i] = (short)f2bf(mu * cs.y);
    }
    #pragma unroll
    for (int i = 0; i < 8; ++i) {
      float mu = softplus_f(bf2f((u16)q1[i]));
      qss += mu * mu;
      float2 cs = pt[8 + i];
      r1[i] = (short)f2bf(mu * cs.x);
      i1[i] = (short)f2bf(mu * cs.y);
    }
    u16* Qrow = Qp + (bh * T_ + t) * 128;
    *(s16x8*)(Qrow + d0)          = r0;
    *(s16x8*)(Qrow + d0 + 8)      = r1;
    *(s16x8*)(Qrow + 64 + d0)     = i0;
    *(s16x8*)(Qrow + 64 + d0 + 8) = i1;
  }
  qss += __shfl_xor(qss, 1);
  qss += __shfl_xor(qss, 2);
  if (j == 0) qn[bh * T_ + t] = sqrtf(qss);

  // ---- V transpose via LDS (swizzled) ----
  {
    s16x8 v0 = *(const s16x8*)(qkvb + qrow + 2048 + d0);
    s16x8 v1 = *(const s16x8*)(qkvb + qrow + 2048 + d0 + 8);
    *(s16x8*)(&Vs[tl][d0])     = v0;
    *(s16x8*)(&Vs[tl][d0 + 8]) = v1;
  }
  __syncthreads();
  if (tid == 0) {
    float mx = 0.f;
    #pragma unroll
    for (int i = 0; i < 64; ++i) mx = fmaxf(mx, knsh[i]);
    atomicMax(knmaxI + bh, __float_as_int(sqrtf(mx)));
  }
  {
    const int d = tid >> 2, jj = tid & 3, ts0 = jj * 16;
    u16* Vrow = Vtp + (bh * 64 + d) * T_;
    int swd = d & 7;
    s16x8 o0, o1;
    #pragma unroll
    for (int i = 0; i < 8; ++i) {
      o0[i] = (short)Vs[ts0 + i][d];
      o1[i] = (short)Vs[ts0 + 8 + i][d];
    }
    int cc0 = ts0 >> 3;
    *(s16x8*)(Vrow + t0 + ((cc0 ^ swd) << 3))       = o0;
    *(s16x8*)(Vrow + t0 + (((cc0 + 1) ^ swd) << 3)) = o1;
  }
}

// ---------------- split flash attention, 32x32, fixed-m, 2-deep pipeline ----------------
__global__ __launch_bounds__(256) void attn_split(
    const u16* __restrict__ Qp, const u16* __restrict__ Kp,
    const u16* __restrict__ Vtp, const float* __restrict__ qn,
    const int* __restrict__ knmaxI, u16* __restrict__ po, float* __restrict__ pl)
{
  const int xcd = (int)blockIdx.x & 7;
  const int idx = (int)blockIdx.x >> 3;      // 0..287
  const int bh = xcd + 8 * (idx / 72);
  const int w72 = idx % 72;
  const int qt = QTC[w72][0], c = QTC[w72][1];
  const int slot = bh * 72 + QTC[w72][2];

  __shared__ u16 smem[2][12288];             // 2 x (K 16KB + Vt 8KB) = 48 KB
  const int tid = threadIdx.x, w = tid >> 6, l = tid & 63;
  const int hi = l >> 5, ln = l & 31;

  const int kbeg = c * 256;
  const int kend0 = (qt + 1) * 128;
  const int kend = kend0 < kbeg + 256 ? kend0 : kbeg + 256;
  const int ntile = (kend - kbeg) >> 6;      // 2 or 4

  const float LS = 0.125f * 1.4426950408889634f;   // scale * log2(e)
  const u16* Kpb = Kp + (size_t)bh * T_ * 128;
  const u16* Vtb = Vtp + (size_t)bh * 64 * T_;

  auto STAGE = [&](int buf, int s0) {
    u16* Kd = smem[buf];
    u16* Vd = smem[buf] + 8192;
    #pragma unroll
    for (int jj = 0; jj < 4; ++jj) {
      int cid = (jj * 4 + w) * 64 + l;         // 0..1023
      int row = cid >> 4, cc = cid & 15;
      gload16(Kd + ((jj * 4 + w) << 9), Kpb + (size_t)(s0 + row) * 128 + cc * 8);
    }
    #pragma unroll
    for (int jj = 0; jj < 2; ++jj) {
      int cid = (jj * 4 + w) * 64 + l;         // 0..511
      int row = cid >> 3, cc = cid & 7;
      gload16(Vd + ((jj * 4 + w) << 9), Vtb + (size_t)row * T_ + s0 + cc * 8);
    }
  };

  STAGE(0, kbeg);                              // tile 0 in flight first

  // ---- Q fragments + fixed m (loads overlap with stage0) ----
  const int q = qt * 128 + w * 32 + ln;
  s16x8 qf[8];
  {
    const u16* qrp = Qp + ((size_t)bh * T_ + q) * 128;
    #pragma unroll
    for (int ks = 0; ks < 8; ++ks)
      qf[ks] = *(const s16x8*)(qrp + ks * 16 + hi * 8);
  }
  const float knm = __int_as_float(knmaxI[bh]);
  const float m = LS * qn[(size_t)bh * T_ + q] * knm;

  STAGE(1, kbeg + 64);                         // tile 1 in flight

  const f32x16 zero16 = {0.f,0.f,0.f,0.f,0.f,0.f,0.f,0.f,
                         0.f,0.f,0.f,0.f,0.f,0.f,0.f,0.f};
  f32x16 o0 = zero16, o1 = zero16;
  float lsum = 0.f;
  const int qminw = qt * 128 + w * 32;

  for (int ti = 0; ti < ntile; ++ti) {
    const int s0 = kbeg + ti * 64;
    if (ti + 1 < ntile)
      asm volatile("s_waitcnt vmcnt(6)" ::: "memory");   // tile-ti (+Q) done
    else
      asm volatile("s_waitcnt vmcnt(0)" ::: "memory");
    __builtin_amdgcn_s_barrier();              // all waves: tile ready
    __builtin_amdgcn_sched_barrier(0);

    const u16* Ks  = smem[ti & 1];
    const u16* Vts = smem[ti & 1] + 8192;

    if (s0 <= qminw + 31) {
      const bool needmask = (s0 + 63) > qminw;

      // ---- QK^T (swapped): C[s][q] ----
      f32x16 sacc0 = zero16, sacc1 = zero16;
      __builtin_amdgcn_s_setprio(1);
      #pragma unroll
      for (int ks = 0; ks < 8; ++ks) {
        int r0_ = ln, r1_ = 32 + ln;
        s16x8 kf0 = *(const s16x8*)(Ks + r0_ * 128 + (((2 * ks + hi) ^ (r0_ & 7)) << 3));
        s16x8 kf1 = *(const s16x8*)(Ks + r1_ * 128 + (((2 * ks + hi) ^ (r1_ & 7)) << 3));
        sacc0 = mfma32(kf0, qf[ks], sacc0);
        sacc1 = mfma32(kf1, qf[ks], sacc1);
      }
      __builtin_amdgcn_s_setprio(0);

      // ---- mask + p = exp2(sc*LS - m) IN PLACE ----
      if (needmask) {
        #pragma unroll
        for (int jj = 0; jj < 16; ++jj) {
          int sg = s0 + (jj & 3) + 8 * (jj >> 2) + 4 * hi;
          if (sg > q)      sacc0[jj] = -3e38f;
          if (sg + 32 > q) sacc1[jj] = -3e38f;
        }
      }
      float rs = 0.f;
      #pragma unroll
      for (int jj = 0; jj < 16; ++jj) {
        float p0 = exp2f(fmaf(sacc0[jj], LS, -m));
        float p1 = exp2f(fmaf(sacc1[jj], LS, -m));
        sacc0[jj] = p0; sacc1[jj] = p1;
        rs += p0 + p1;
      }
      lsum += rs;

      // ---- P -> bf16 A-frags via cvt_pk + permlane32_swap ----
      s16x8 pa[4];
      #pragma unroll
      for (int ks = 0; ks < 4; ++ks) {
        const int bb = (ks & 1) * 8;
        unsigned a0, a1, b0v, b1v;
        if (ks < 2) {
          a0  = cvtpk(sacc0[bb + 0], sacc0[bb + 1]);
          a1  = cvtpk(sacc0[bb + 2], sacc0[bb + 3]);
          b0v = cvtpk(sacc0[bb + 4], sacc0[bb + 5]);
          b1v = cvtpk(sacc0[bb + 6], sacc0[bb + 7]);
        } else {
          a0  = cvtpk(sacc1[bb + 0], sacc1[bb + 1]);
          a1  = cvtpk(sacc1[bb + 2], sacc1[bb + 3]);
          b0v = cvtpk(sacc1[bb + 4], sacc1[bb + 5]);
          b1v = cvtpk(sacc1[bb + 6], sacc1[bb + 7]);
        }
        asm("v_permlane32_swap_b32 %0, %1" : "+v"(a0), "+v"(b0v));
        asm("v_permlane32_swap_b32 %0, %1" : "+v"(a1), "+v"(b1v));
        union { unsigned u[4]; s16x8 v; } pu;
        pu.u[0] = a0; pu.u[1] = a1; pu.u[2] = b0v; pu.u[3] = b1v;
        pa[ks] = pu.v;
      }

      // ---- PV: o[q][d] += P x V ----
      __builtin_amdgcn_s_setprio(1);
      #pragma unroll
      for (int ks = 0; ks < 4; ++ks) {
        int rd0 = ln, rd1 = 32 + ln;
        s16x8 vb0 = *(const s16x8*)(Vts + rd0 * 64 + (((2 * ks + hi) ^ (rd0 & 7)) << 3));
        s16x8 vb1 = *(const s16x8*)(Vts + rd1 * 64 + (((2 * ks + hi) ^ (rd1 & 7)) << 3));
        o0 = mfma32(pa[ks], vb0, o0);
        o1 = mfma32(pa[ks], vb1, o1);
      }
      __builtin_amdgcn_s_setprio(0);
    }
    __builtin_amdgcn_s_barrier();              // all waves done reading buf
    if (ti + 2 < ntile) STAGE(ti & 1, s0 + 128);
  }

  // ---- epilogue: write partials (o bf16, l f32) ----
  lsum += __shfl_xor(lsum, 32);
  u16* pob = po + (size_t)slot * 8192;
  #pragma unroll
  for (int jj = 0; jj < 16; ++jj) {
    int row = w * 32 + 4 * hi + (jj & 3) + 8 * (jj >> 2);
    pob[row * 64 + ln]      = f2bf(o0[jj]);
    pob[row * 64 + 32 + ln] = f2bf(o1[jj]);
  }
  if (hi == 0)
    pl[(size_t)slot * 128 + w * 32 + ln] = lsum;
}

// ---------------- combine partials -> yb (XCD-pinned to match writers) ----------------
__global__ __launch_bounds__(256) void attn_combine(
    const u16* __restrict__ po, const float* __restrict__ pl,
    u16* __restrict__ yb)
{
  const int xcd = (int)blockIdx.x & 7;
  const int i = (int)blockIdx.x >> 3;        // 0..63
  const int bh = xcd + 8 * (i & 3);          // same XCD as the writers of bh
  const int qt = 15 - (i >> 2);              // heavy first
  const int b = bh >> 4, h = bh & 15;
  const int nch = (qt + 2) >> 1;             // ceil((qt+1)/2)
  const int base = bh * 72 + OFFT[qt];
  const int t = threadIdx.x;
  const int row = t >> 1, d0 = (t & 1) * 32;

  float acc[32];
  #pragma unroll
  for (int i2 = 0; i2 < 32; ++i2) acc[i2] = 0.f;
  float ls = 0.f;
  for (int c = 0; c < nch; ++c) {
    const u16* pr = po + (size_t)(base + c) * 8192 + row * 64 + d0;
    #pragma unroll
    for (int v = 0; v < 4; ++v) {
      s16x8 x = *(const s16x8*)(pr + v * 8);
      #pragma unroll
      for (int i2 = 0; i2 < 8; ++i2) acc[v * 8 + i2] += bf2f((u16)x[i2]);
    }
    ls += pl[(size_t)(base + c) * 128 + row];
  }
  float inv = 1.f / ls;
  int qrow = qt * 128 + row;
  size_t rb = (size_t)(b * T_ + qrow) * 1024 + h * 64;
  #pragma unroll
  for (int v = 0; v < 4; ++v) {
    int ch = ((d0 >> 3) + v) ^ (qrow & 7);
    s16x8 o;
    #pragma unroll
    for (int i2 = 0; i2 < 8; ++i2) o[i2] = (short)f2bf(acc[v * 8 + i2] * inv);
    *(s16x8*)(yb + rb + (ch << 3)) = o;
  }
}

// ---------------------------------------------------------------------------
extern "C" void kernel_launch(void* const* d_in, const int* in_sizes, int n_in,
                              void* d_out, int out_size, void* d_ws, size_t ws_size,
                              hipStream_t stream)
{
  const float* x      = (const float*)d_in[0];   // (B,T,C)
  const float* w_attn = (const float*)d_in[1];   // (3C,C)
  const float* w_proj = (const float*)d_in[2];   // (C,C)
  const float* delta  = (const float*)d_in[3];   // (H,D)
  float* out = (float*)d_out;

  char* p = (char*)d_ws;
  // --- phase-1 region (dead after pope_prep) -> reused as po by attn ---
  u16* qkvb   = (u16*)p;                                        // 24 MB
  u16* xb     = (u16*)(p + (size_t)4096 * 3072 * 2);            //  8 MB
  u16* wab    = (u16*)(p + (size_t)4096 * 3072 * 2 + (size_t)4096 * 1024 * 2); // 6 MB
  u16* po     = (u16*)p;        // 2304 slots * 16KB = 36.9 MB, aliases the above
  p += (size_t)(4096 * 3072 + 4096 * 1024 + 3072 * 1024) * 2;   // 38.8 MB
  // --- persistent region ---
  u16* wpb    = (u16*)p;  p += (size_t)1024 * 1024 * 2;
  u16* yb     = (u16*)p;  p += (size_t)4096 * 1024 * 2;
  u16* Kp     = (u16*)p;  p += (size_t)B_ * HN_ * T_ * 128 * 2;
  u16* Vtp    = (u16*)p;  p += (size_t)B_ * HN_ * 64 * T_ * 2;
  u16* Qp     = (u16*)p;  p += (size_t)B_ * HN_ * T_ * 128 * 2;
  float* postab = (float*)p; p += (size_t)T_ * 64 * 2 * 4;
  float* dtab   = (float*)p; p += (size_t)HN_ * 64 * 2 * 4;
  float* qn     = (float*)p; p += (size_t)B_ * HN_ * T_ * 4;
  float* pl     = (float*)p; p += (size_t)2304 * 128 * 4;
  int*   knmaxI = (int*)p;   p += 32 * 4;

  // fused prep: conv x/w_attn/w_proj + trig tables + knmax zero (1 launch)
  prep_all<<<dim3((1048576 + T_ * 64) / 256), 256, 0, stream>>>(
      x, w_attn, w_proj, delta, xb, wab, wpb, postab, dtab, knmaxI);

  gemm_nt_mfma256<<<dim3(3072 / 256, 4096 / 128), 512, 0, stream>>>(
      xb, wab, qkvb, 3072);
  pope_prep<<<dim3(T_ / 64, HN_, B_), 256, 0, stream>>>(qkvb, postab, dtab, Kp, Vtp,
                                                        Qp, qn, knmaxI);
  attn_split<<<dim3(2304), 256, 0, stream>>>(Qp, Kp, Vtp, qn, knmaxI, po, pl);
  attn_combine<<<dim3(512), 256, 0, stream>>>(po, pl, yb);
  gemm_nt_mfma<1><<<dim3(1024 / 128, 4096 / 128), 256, 0, stream>>>(yb, wpb, out, 1024);
}

// Round 13
// 156.185 us; speedup vs baseline: 1.0998x; 1.0998x over previous
//
#include <hip/hip_runtime.h>
#include <math.h>

typedef short s16x8 __attribute__((ext_vector_type(8)));
typedef float f32x4 __attribute__((ext_vector_type(4)));
typedef float f32x16 __attribute__((ext_vector_type(16)));
typedef unsigned short u16;

#define B_ 2
#define T_ 2048
#define HN_ 16

// ---------------- helpers ----------------
__device__ __forceinline__ u16 f2bf(float f) {
  union { float f; unsigned u; } v; v.f = f;
  unsigned r = v.u + 0x7FFFu + ((v.u >> 16) & 1u);   // RNE (finite inputs)
  return (u16)(r >> 16);
}
__device__ __forceinline__ float bf2f(u16 b) {
  union { unsigned u; float f; } v; v.u = ((unsigned)b) << 16;
  return v.f;
}
__device__ __forceinline__ float softplus_f(float v) {
  return fmaxf(v, 0.f) + __logf(1.f + __expf(-fabsf(v)));
}
__device__ __forceinline__ f32x4 mfma16(s16x8 a, s16x8 b, f32x4 c) {
  return __builtin_amdgcn_mfma_f32_16x16x32_bf16(a, b, c, 0, 0, 0);
}
__device__ __forceinline__ f32x16 mfma32(s16x8 a, s16x8 b, f32x16 c) {
  return __builtin_amdgcn_mfma_f32_32x32x16_bf16(a, b, c, 0, 0, 0);
}
__device__ __forceinline__ void gload16(void* lds, const void* g) {
  __builtin_amdgcn_global_load_lds(
      (const __attribute__((address_space(1))) unsigned int*)g,
      (__attribute__((address_space(3))) unsigned int*)lds, 16, 0, 0);
}
__device__ __forceinline__ unsigned cvtpk(float lo, float hi) {
  unsigned r;
  asm("v_cvt_pk_bf16_f32 %0, %1, %2" : "=v"(r) : "v"(lo), "v"(hi));
  return r;
}

// work list: (qt, c, slot) with 256-key chunks; qt descending (heavy first).
__device__ __constant__ unsigned char QTC[72][3] = {
  {15,0,64},{15,1,65},{15,2,66},{15,3,67},{15,4,68},{15,5,69},{15,6,70},{15,7,71},
  {14,0,56},{14,1,57},{14,2,58},{14,3,59},{14,4,60},{14,5,61},{14,6,62},{14,7,63},
  {13,0,49},{13,1,50},{13,2,51},{13,3,52},{13,4,53},{13,5,54},{13,6,55},
  {12,0,42},{12,1,43},{12,2,44},{12,3,45},{12,4,46},{12,5,47},{12,6,48},
  {11,0,36},{11,1,37},{11,2,38},{11,3,39},{11,4,40},{11,5,41},
  {10,0,30},{10,1,31},{10,2,32},{10,3,33},{10,4,34},{10,5,35},
  {9,0,25},{9,1,26},{9,2,27},{9,3,28},{9,4,29},
  {8,0,20},{8,1,21},{8,2,22},{8,3,23},{8,4,24},
  {7,0,16},{7,1,17},{7,2,18},{7,3,19},
  {6,0,12},{6,1,13},{6,2,14},{6,3,15},
  {5,0,9},{5,1,10},{5,2,11},
  {4,0,6},{4,1,7},{4,2,8},
  {3,0,4},{3,1,5},
  {2,0,2},{2,1,3},
  {1,0,1},
  {0,0,0}
};
__device__ __constant__ unsigned char OFFT[16] =
  {0,1,2,4,6,9,12,16,20,25,30,36,42,49,56,64};

// ---------------- fused prep: conv x / w_attn / w_proj + tables + knmax ----------------
__device__ __forceinline__ void conv_one(
    const float* __restrict__ in, u16* __restrict__ out, int c)
{
  int row = c >> 7, cc = c & 127;           // 128 chunks per 1024-elem row
  int ks = cc >> 3, ch = cc & 7;
  const float4* src = (const float4*)(in + ((size_t)row << 10) + (cc << 3));
  float4 a = src[0], b = src[1];
  s16x8 o;
  o[0] = (short)f2bf(a.x); o[1] = (short)f2bf(a.y);
  o[2] = (short)f2bf(a.z); o[3] = (short)f2bf(a.w);
  o[4] = (short)f2bf(b.x); o[5] = (short)f2bf(b.y);
  o[6] = (short)f2bf(b.z); o[7] = (short)f2bf(b.w);
  *(s16x8*)(out + ((size_t)row << 10) + (ks << 6) + ((ch ^ (row & 7)) << 3)) = o;
}

__global__ __launch_bounds__(256) void prep_all(
    const float* __restrict__ x, const float* __restrict__ w_attn,
    const float* __restrict__ w_proj, const float* __restrict__ delta,
    u16* __restrict__ xb, u16* __restrict__ wab, u16* __restrict__ wpb,
    float* __restrict__ postab, float* __restrict__ dtab, int* __restrict__ knmaxI)
{
  const int gid = blockIdx.x * 256 + threadIdx.x;
  if (gid < 32) knmaxI[gid] = 0;
  if (gid < 524288) {                        // x: 4096*128 chunks
    conv_one(x, xb, gid);
  } else if (gid < 917504) {                 // w_attn: 3072*128
    conv_one(w_attn, wab, gid - 524288);
  } else if (gid < 1048576) {                // w_proj: 1024*128
    conv_one(w_proj, wpb, gid - 917504);
  } else {                                   // tables: T_*64
    int idx = gid - 1048576;
    int t = idx >> 6, d = idx & 63;
    float invf = powf(10000.f, -(float)d * (1.0f / 64.0f));
    float ang = (float)t * invf;
    float sp, cp;
    sincosf(ang, &sp, &cp);
    postab[idx * 2 + 0] = cp;
    postab[idx * 2 + 1] = sp;
    if (idx < HN_ * 64) {
      float dl = delta[idx];
      dl = fminf(fmaxf(dl, -6.2831853071795865f), 0.f);
      float sd, cd;
      sincosf(dl, &sd, &cd);
      dtab[idx * 2 + 0] = cd;
      dtab[idx * 2 + 1] = sd;
    }
  }
}

// ---------------- bf16 MFMA GEMM (NT), 128x128, 4 waves ----------------
template<int OUTK>
__global__ __launch_bounds__(256) void gemm_nt_mfma(
    const u16* __restrict__ A, const u16* __restrict__ Bw,
    void* __restrict__ Cout, int N)
{
  __shared__ u16 As[128 * 64];
  __shared__ u16 Bs[128 * 64];
  const int tid = threadIdx.x;
  const int w = tid >> 6, l = tid & 63, g = l >> 4;
  const int bm = blockIdx.y * 128, bn = blockIdx.x * 128;
  const int wr = w >> 1, wc = w & 1;
  const int K = 1024;

  const f32x4 zero = {0.f, 0.f, 0.f, 0.f};
  f32x4 acc[4][4];
  #pragma unroll
  for (int mt = 0; mt < 4; ++mt)
    #pragma unroll
    for (int nt = 0; nt < 4; ++nt) acc[mt][nt] = zero;

  for (int kt = 0; kt < K; kt += 64) {
    __syncthreads();
    #pragma unroll
    for (int j = 0; j < 4; ++j) {
      int cid = (j * 4 + w) * 64 + l;           // chunk 0..1023
      int row = cid >> 3, cc = cid & 7;
      gload16(As + ((j * 4 + w) << 9), A  + (size_t)(bm + row) * K + kt + cc * 8);
      gload16(Bs + ((j * 4 + w) << 9), Bw + (size_t)(bn + row) * K + kt + cc * 8);
    }
    __syncthreads();
    #pragma unroll
    for (int ks = 0; ks < 2; ++ks) {
      s16x8 af[4], bfr[4];
      #pragma unroll
      for (int mt = 0; mt < 4; ++mt) {
        int rr = wr * 64 + mt * 16 + (l & 15);
        af[mt] = *(const s16x8*)(As + rr * 64 + (((ks * 4 + g) ^ (rr & 7)) << 3));
      }
      #pragma unroll
      for (int nt = 0; nt < 4; ++nt) {
        int rr = wc * 64 + nt * 16 + (l & 15);
        bfr[nt] = *(const s16x8*)(Bs + rr * 64 + (((ks * 4 + g) ^ (rr & 7)) << 3));
      }
      #pragma unroll
      for (int mt = 0; mt < 4; ++mt)
        #pragma unroll
        for (int nt = 0; nt < 4; ++nt)
          acc[mt][nt] = mfma16(af[mt], bfr[nt], acc[mt][nt]);
    }
  }

  #pragma unroll
  for (int mt = 0; mt < 4; ++mt)
    #pragma unroll
    for (int nt = 0; nt < 4; ++nt)
      #pragma unroll
      for (int r = 0; r < 4; ++r) {
        int row = bm + wr * 64 + mt * 16 + g * 4 + r;
        int col = bn + wc * 64 + nt * 16 + (l & 15);
        if (OUTK == 0)
          ((u16*)Cout)[(size_t)row * N + col] = f2bf(acc[mt][nt][r]);
        else
          ((float*)Cout)[(size_t)row * N + col] = acc[mt][nt][r];
      }
}

// ---------------- PoPE prepass ----------------
__global__ __launch_bounds__(256) void pope_prep(
    const u16* __restrict__ qkvb, const float* __restrict__ postab,
    const float* __restrict__ dtab, u16* __restrict__ Kp, u16* __restrict__ Vtp,
    u16* __restrict__ Qp, float* __restrict__ qn, int* __restrict__ knmaxI)
{
  __shared__ u16 Vs[64][72];
  __shared__ float knsh[64];
  const int tb = blockIdx.x, h = blockIdx.y, b = blockIdx.z;
  const int t0 = tb * 64, tid = threadIdx.x;
  const int tl = tid >> 2, j = tid & 3, d0 = j * 16;
  const int t = t0 + tl;
  const size_t bh = (size_t)b * HN_ + h;
  const size_t qrow = (size_t)(b * T_ + t) * 3072 + h * 64;
  const float2* pt = (const float2*)postab + (size_t)t * 64 + d0;

  // ---- K with phases (swizzled) + k-norm ----
  float kss = 0.f;
  {
    s16x8 k0 = *(const s16x8*)(qkvb + qrow + 1024 + d0);
    s16x8 k1 = *(const s16x8*)(qkvb + qrow + 1024 + d0 + 8);
    const float2* dt = (const float2*)dtab + h * 64 + d0;
    s16x8 r0, r1, i0, i1;
    #pragma unroll
    for (int i = 0; i < 8; ++i) {
      float mu = softplus_f(bf2f((u16)k0[i]));
      kss += mu * mu;
      float2 cs = pt[i]; float2 dc = dt[i];
      r0[i] = (short)f2bf(mu * (cs.x * dc.x - cs.y * dc.y));
      i0[i] = (short)f2bf(mu * (cs.y * dc.x + cs.x * dc.y));
    }
    #pragma unroll
    for (int i = 0; i < 8; ++i) {
      float mu = softplus_f(bf2f((u16)k1[i]));
      kss += mu * mu;
      float2 cs = pt[8 + i]; float2 dc = dt[8 + i];
      r1[i] = (short)f2bf(mu * (cs.x * dc.x - cs.y * dc.y));
      i1[i] = (short)f2bf(mu * (cs.y * dc.x + cs.x * dc.y));
    }
    u16* Krow = Kp + (bh * T_ + t) * 128;
    int sw = t & 7;
    int c0 = d0 >> 3;
    *(s16x8*)(Krow + ((c0 ^ sw) << 3))       = r0;
    *(s16x8*)(Krow + (((c0 + 1) ^ sw) << 3)) = r1;
    *(s16x8*)(Krow + (((c0 + 8) ^ sw) << 3)) = i0;
    *(s16x8*)(Krow + (((c0 + 9) ^ sw) << 3)) = i1;
  }
  kss += __shfl_xor(kss, 1);
  kss += __shfl_xor(kss, 2);
  if (j == 0) knsh[tl] = kss;

  // ---- Q with pos phase (plain) + q-norm ----
  float qss = 0.f;
  {
    s16x8 q0 = *(const s16x8*)(qkvb + qrow + d0);
    s16x8 q1 = *(const s16x8*)(qkvb + qrow + d0 + 8);
    s16x8 r0, r1, i0, i1;
    #pragma unroll
    for (int i = 0; i < 8; ++i) {
      float mu = softplus_f(bf2f((u16)q0[i]));
      qss += mu * mu;
      float2 cs = pt[i];
      r0[i] = (short)f2bf(mu * cs.x);
      i0[i] = (short)f2bf(mu * cs.y);
    }
    #pragma unroll
    for (int i = 0; i < 8; ++i) {
      float mu = softplus_f(bf2f((u16)q1[i]));
      qss += mu * mu;
      float2 cs = pt[8 + i];
      r1[i] = (short)f2bf(mu * cs.x);
      i1[i] = (short)f2bf(mu * cs.y);
    }
    u16* Qrow = Qp + (bh * T_ + t) * 128;
    *(s16x8*)(Qrow + d0)          = r0;
    *(s16x8*)(Qrow + d0 + 8)      = r1;
    *(s16x8*)(Qrow + 64 + d0)     = i0;
    *(s16x8*)(Qrow + 64 + d0 + 8) = i1;
  }
  qss += __shfl_xor(qss, 1);
  qss += __shfl_xor(qss, 2);
  if (j == 0) qn[bh * T_ + t] = sqrtf(qss);

  // ---- V transpose via LDS (swizzled) ----
  {
    s16x8 v0 = *(const s16x8*)(qkvb + qrow + 2048 + d0);
    s16x8 v1 = *(const s16x8*)(qkvb + qrow + 2048 + d0 + 8);
    *(s16x8*)(&Vs[tl][d0])     = v0;
    *(s16x8*)(&Vs[tl][d0 + 8]) = v1;
  }
  __syncthreads();
  if (tid == 0) {
    float mx = 0.f;
    #pragma unroll
    for (int i = 0; i < 64; ++i) mx = fmaxf(mx, knsh[i]);
    atomicMax(knmaxI + bh, __float_as_int(sqrtf(mx)));
  }
  {
    const int d = tid >> 2, jj = tid & 3, ts0 = jj * 16;
    u16* Vrow = Vtp + (bh * 64 + d) * T_;
    int swd = d & 7;
    s16x8 o0, o1;
    #pragma unroll
    for (int i = 0; i < 8; ++i) {
      o0[i] = (short)Vs[ts0 + i][d];
      o1[i] = (short)Vs[ts0 + 8 + i][d];
    }
    int cc0 = ts0 >> 3;
    *(s16x8*)(Vrow + t0 + ((cc0 ^ swd) << 3))       = o0;
    *(s16x8*)(Vrow + t0 + (((cc0 + 1) ^ swd) << 3)) = o1;
  }
}

// ---------------- split flash attention, 32x32, fixed-m, 2-deep pipeline ----------------
__global__ __launch_bounds__(256) void attn_split(
    const u16* __restrict__ Qp, const u16* __restrict__ Kp,
    const u16* __restrict__ Vtp, const float* __restrict__ qn,
    const int* __restrict__ knmaxI, u16* __restrict__ po, float* __restrict__ pl)
{
  const int xcd = (int)blockIdx.x & 7;
  const int idx = (int)blockIdx.x >> 3;      // 0..287
  const int bh = xcd + 8 * (idx / 72);
  const int w72 = idx % 72;
  const int qt = QTC[w72][0], c = QTC[w72][1];
  const int slot = bh * 72 + QTC[w72][2];

  __shared__ u16 smem[2][12288];             // 2 x (K 16KB + Vt 8KB) = 48 KB
  const int tid = threadIdx.x, w = tid >> 6, l = tid & 63;
  const int hi = l >> 5, ln = l & 31;

  const int kbeg = c * 256;
  const int kend0 = (qt + 1) * 128;
  const int kend = kend0 < kbeg + 256 ? kend0 : kbeg + 256;
  const int ntile = (kend - kbeg) >> 6;      // 2 or 4

  const float LS = 0.125f * 1.4426950408889634f;   // scale * log2(e)
  const u16* Kpb = Kp + (size_t)bh * T_ * 128;
  const u16* Vtb = Vtp + (size_t)bh * 64 * T_;

  auto STAGE = [&](int buf, int s0) {
    u16* Kd = smem[buf];
    u16* Vd = smem[buf] + 8192;
    #pragma unroll
    for (int jj = 0; jj < 4; ++jj) {
      int cid = (jj * 4 + w) * 64 + l;         // 0..1023
      int row = cid >> 4, cc = cid & 15;
      gload16(Kd + ((jj * 4 + w) << 9), Kpb + (size_t)(s0 + row) * 128 + cc * 8);
    }
    #pragma unroll
    for (int jj = 0; jj < 2; ++jj) {
      int cid = (jj * 4 + w) * 64 + l;         // 0..511
      int row = cid >> 3, cc = cid & 7;
      gload16(Vd + ((jj * 4 + w) << 9), Vtb + (size_t)row * T_ + s0 + cc * 8);
    }
  };

  STAGE(0, kbeg);                              // tile 0 in flight first

  // ---- Q fragments + fixed m (loads overlap with stage0) ----
  const int q = qt * 128 + w * 32 + ln;
  s16x8 qf[8];
  {
    const u16* qrp = Qp + ((size_t)bh * T_ + q) * 128;
    #pragma unroll
    for (int ks = 0; ks < 8; ++ks)
      qf[ks] = *(const s16x8*)(qrp + ks * 16 + hi * 8);
  }
  const float knm = __int_as_float(knmaxI[bh]);
  const float m = LS * qn[(size_t)bh * T_ + q] * knm;

  STAGE(1, kbeg + 64);                         // tile 1 in flight

  const f32x16 zero16 = {0.f,0.f,0.f,0.f,0.f,0.f,0.f,0.f,
                         0.f,0.f,0.f,0.f,0.f,0.f,0.f,0.f};
  f32x16 o0 = zero16, o1 = zero16;
  float lsum = 0.f;
  const int qminw = qt * 128 + w * 32;

  for (int ti = 0; ti < ntile; ++ti) {
    const int s0 = kbeg + ti * 64;
    if (ti + 1 < ntile)
      asm volatile("s_waitcnt vmcnt(6)" ::: "memory");   // tile-ti (+Q) done
    else
      asm volatile("s_waitcnt vmcnt(0)" ::: "memory");
    __builtin_amdgcn_s_barrier();              // all waves: tile ready
    __builtin_amdgcn_sched_barrier(0);

    const u16* Ks  = smem[ti & 1];
    const u16* Vts = smem[ti & 1] + 8192;

    if (s0 <= qminw + 31) {
      const bool needmask = (s0 + 63) > qminw;

      // ---- QK^T (swapped): C[s][q] ----
      f32x16 sacc0 = zero16, sacc1 = zero16;
      __builtin_amdgcn_s_setprio(1);
      #pragma unroll
      for (int ks = 0; ks < 8; ++ks) {
        int r0_ = ln, r1_ = 32 + ln;
        s16x8 kf0 = *(const s16x8*)(Ks + r0_ * 128 + (((2 * ks + hi) ^ (r0_ & 7)) << 3));
        s16x8 kf1 = *(const s16x8*)(Ks + r1_ * 128 + (((2 * ks + hi) ^ (r1_ & 7)) << 3));
        sacc0 = mfma32(kf0, qf[ks], sacc0);
        sacc1 = mfma32(kf1, qf[ks], sacc1);
      }
      __builtin_amdgcn_s_setprio(0);

      // ---- mask + p = exp2(sc*LS - m) IN PLACE ----
      if (needmask) {
        #pragma unroll
        for (int jj = 0; jj < 16; ++jj) {
          int sg = s0 + (jj & 3) + 8 * (jj >> 2) + 4 * hi;
          if (sg > q)      sacc0[jj] = -3e38f;
          if (sg + 32 > q) sacc1[jj] = -3e38f;
        }
      }
      float rs = 0.f;
      #pragma unroll
      for (int jj = 0; jj < 16; ++jj) {
        float p0 = exp2f(fmaf(sacc0[jj], LS, -m));
        float p1 = exp2f(fmaf(sacc1[jj], LS, -m));
        sacc0[jj] = p0; sacc1[jj] = p1;
        rs += p0 + p1;
      }
      lsum += rs;

      // ---- P -> bf16 A-frags via cvt_pk + permlane32_swap ----
      s16x8 pa[4];
      #pragma unroll
      for (int ks = 0; ks < 4; ++ks) {
        const int bb = (ks & 1) * 8;
        unsigned a0, a1, b0v, b1v;
        if (ks < 2) {
          a0  = cvtpk(sacc0[bb + 0], sacc0[bb + 1]);
          a1  = cvtpk(sacc0[bb + 2], sacc0[bb + 3]);
          b0v = cvtpk(sacc0[bb + 4], sacc0[bb + 5]);
          b1v = cvtpk(sacc0[bb + 6], sacc0[bb + 7]);
        } else {
          a0  = cvtpk(sacc1[bb + 0], sacc1[bb + 1]);
          a1  = cvtpk(sacc1[bb + 2], sacc1[bb + 3]);
          b0v = cvtpk(sacc1[bb + 4], sacc1[bb + 5]);
          b1v = cvtpk(sacc1[bb + 6], sacc1[bb + 7]);
        }
        asm("v_permlane32_swap_b32 %0, %1" : "+v"(a0), "+v"(b0v));
        asm("v_permlane32_swap_b32 %0, %1" : "+v"(a1), "+v"(b1v));
        union { unsigned u[4]; s16x8 v; } pu;
        pu.u[0] = a0; pu.u[1] = a1; pu.u[2] = b0v; pu.u[3] = b1v;
        pa[ks] = pu.v;
      }

      // ---- PV: o[q][d] += P x V ----
      __builtin_amdgcn_s_setprio(1);
      #pragma unroll
      for (int ks = 0; ks < 4; ++ks) {
        int rd0 = ln, rd1 = 32 + ln;
        s16x8 vb0 = *(const s16x8*)(Vts + rd0 * 64 + (((2 * ks + hi) ^ (rd0 & 7)) << 3));
        s16x8 vb1 = *(const s16x8*)(Vts + rd1 * 64 + (((2 * ks + hi) ^ (rd1 & 7)) << 3));
        o0 = mfma32(pa[ks], vb0, o0);
        o1 = mfma32(pa[ks], vb1, o1);
      }
      __builtin_amdgcn_s_setprio(0);
    }
    __builtin_amdgcn_s_barrier();              // all waves done reading buf
    if (ti + 2 < ntile) STAGE(ti & 1, s0 + 128);
  }

  // ---- epilogue: write partials (o bf16, l f32) ----
  lsum += __shfl_xor(lsum, 32);
  u16* pob = po + (size_t)slot * 8192;
  #pragma unroll
  for (int jj = 0; jj < 16; ++jj) {
    int row = w * 32 + 4 * hi + (jj & 3) + 8 * (jj >> 2);
    pob[row * 64 + ln]      = f2bf(o0[jj]);
    pob[row * 64 + 32 + ln] = f2bf(o1[jj]);
  }
  if (hi == 0)
    pl[(size_t)slot * 128 + w * 32 + ln] = lsum;
}

// ---------------- combine partials -> yb (XCD-pinned to match writers) ----------------
__global__ __launch_bounds__(256) void attn_combine(
    const u16* __restrict__ po, const float* __restrict__ pl,
    u16* __restrict__ yb)
{
  const int xcd = (int)blockIdx.x & 7;
  const int i = (int)blockIdx.x >> 3;        // 0..63
  const int bh = xcd + 8 * (i & 3);          // same XCD as the writers of bh
  const int qt = 15 - (i >> 2);              // heavy first
  const int b = bh >> 4, h = bh & 15;
  const int nch = (qt + 2) >> 1;             // ceil((qt+1)/2)
  const int base = bh * 72 + OFFT[qt];
  const int t = threadIdx.x;
  const int row = t >> 1, d0 = (t & 1) * 32;

  float acc[32];
  #pragma unroll
  for (int i2 = 0; i2 < 32; ++i2) acc[i2] = 0.f;
  float ls = 0.f;
  for (int c = 0; c < nch; ++c) {
    const u16* pr = po + (size_t)(base + c) * 8192 + row * 64 + d0;
    #pragma unroll
    for (int v = 0; v < 4; ++v) {
      s16x8 x = *(const s16x8*)(pr + v * 8);
      #pragma unroll
      for (int i2 = 0; i2 < 8; ++i2) acc[v * 8 + i2] += bf2f((u16)x[i2]);
    }
    ls += pl[(size_t)(base + c) * 128 + row];
  }
  float inv = 1.f / ls;
  int qrow = qt * 128 + row;
  size_t rb = (size_t)(b * T_ + qrow) * 1024 + h * 64;
  #pragma unroll
  for (int v = 0; v < 4; ++v) {
    int ch = ((d0 >> 3) + v) ^ (qrow & 7);
    s16x8 o;
    #pragma unroll
    for (int i2 = 0; i2 < 8; ++i2) o[i2] = (short)f2bf(acc[v * 8 + i2] * inv);
    *(s16x8*)(yb + rb + (ch << 3)) = o;
  }
}

// ---------------------------------------------------------------------------
extern "C" void kernel_launch(void* const* d_in, const int* in_sizes, int n_in,
                              void* d_out, int out_size, void* d_ws, size_t ws_size,
                              hipStream_t stream)
{
  const float* x      = (const float*)d_in[0];   // (B,T,C)
  const float* w_attn = (const float*)d_in[1];   // (3C,C)
  const float* w_proj = (const float*)d_in[2];   // (C,C)
  const float* delta  = (const float*)d_in[3];   // (H,D)
  float* out = (float*)d_out;

  char* p = (char*)d_ws;
  // --- phase-1 region (dead after pope_prep) -> reused as po by attn ---
  u16* qkvb   = (u16*)p;                                        // 24 MB
  u16* xb     = (u16*)(p + (size_t)4096 * 3072 * 2);            //  8 MB
  u16* wab    = (u16*)(p + (size_t)4096 * 3072 * 2 + (size_t)4096 * 1024 * 2); // 6 MB
  u16* po     = (u16*)p;        // 2304 slots * 16KB = 36.9 MB, aliases the above
  p += (size_t)(4096 * 3072 + 4096 * 1024 + 3072 * 1024) * 2;   // 38.8 MB
  // --- persistent region ---
  u16* wpb    = (u16*)p;  p += (size_t)1024 * 1024 * 2;
  u16* yb     = (u16*)p;  p += (size_t)4096 * 1024 * 2;
  u16* Kp     = (u16*)p;  p += (size_t)B_ * HN_ * T_ * 128 * 2;
  u16* Vtp    = (u16*)p;  p += (size_t)B_ * HN_ * 64 * T_ * 2;
  u16* Qp     = (u16*)p;  p += (size_t)B_ * HN_ * T_ * 128 * 2;
  float* postab = (float*)p; p += (size_t)T_ * 64 * 2 * 4;
  float* dtab   = (float*)p; p += (size_t)HN_ * 64 * 2 * 4;
  float* qn     = (float*)p; p += (size_t)B_ * HN_ * T_ * 4;
  float* pl     = (float*)p; p += (size_t)2304 * 128 * 4;
  int*   knmaxI = (int*)p;   p += 32 * 4;

  // fused prep: conv x/w_attn/w_proj + trig tables + knmax zero (1 launch)
  prep_all<<<dim3((1048576 + T_ * 64) / 256), 256, 0, stream>>>(
      x, w_attn, w_proj, delta, xb, wab, wpb, postab, dtab, knmaxI);

  gemm_nt_mfma<0><<<dim3(3072 / 128, 4096 / 128), 256, 0, stream>>>(xb, wab, qkvb, 3072);
  pope_prep<<<dim3(T_ / 64, HN_, B_), 256, 0, stream>>>(qkvb, postab, dtab, Kp, Vtp,
                                                        Qp, qn, knmaxI);
  attn_split<<<dim3(2304), 256, 0, stream>>>(Qp, Kp, Vtp, qn, knmaxI, po, pl);
  attn_combine<<<dim3(512), 256, 0, stream>>>(po, pl, yb);
  gemm_nt_mfma<1><<<dim3(1024 / 128, 4096 / 128), 256, 0, stream>>>(yb, wpb, out, 1024);
}

// Round 14
// 152.201 us; speedup vs baseline: 1.1286x; 1.0262x over previous
//
#include <hip/hip_runtime.h>
#include <math.h>

typedef short s16x8 __attribute__((ext_vector_type(8)));
typedef float f32x4 __attribute__((ext_vector_type(4)));
typedef float f32x16 __attribute__((ext_vector_type(16)));
typedef unsigned short u16;

#define B_ 2
#define T_ 2048
#define HN_ 16

// ---------------- helpers ----------------
__device__ __forceinline__ u16 f2bf(float f) {
  union { float f; unsigned u; } v; v.f = f;
  unsigned r = v.u + 0x7FFFu + ((v.u >> 16) & 1u);   // RNE (finite inputs)
  return (u16)(r >> 16);
}
__device__ __forceinline__ float bf2f(u16 b) {
  union { unsigned u; float f; } v; v.u = ((unsigned)b) << 16;
  return v.f;
}
__device__ __forceinline__ float softplus_f(float v) {
  return fmaxf(v, 0.f) + __logf(1.f + __expf(-fabsf(v)));
}
__device__ __forceinline__ f32x4 mfma16(s16x8 a, s16x8 b, f32x4 c) {
  return __builtin_amdgcn_mfma_f32_16x16x32_bf16(a, b, c, 0, 0, 0);
}
__device__ __forceinline__ f32x16 mfma32(s16x8 a, s16x8 b, f32x16 c) {
  return __builtin_amdgcn_mfma_f32_32x32x16_bf16(a, b, c, 0, 0, 0);
}
__device__ __forceinline__ void gload16(void* lds, const void* g) {
  __builtin_amdgcn_global_load_lds(
      (const __attribute__((address_space(1))) unsigned int*)g,
      (__attribute__((address_space(3))) unsigned int*)lds, 16, 0, 0);
}
__device__ __forceinline__ unsigned cvtpk(float lo, float hi) {
  unsigned r;
  asm("v_cvt_pk_bf16_f32 %0, %1, %2" : "=v"(r) : "v"(lo), "v"(hi));
  return r;
}

// work list: (qt, c, slot) with 256-key chunks; qt descending (heavy first).
__device__ __constant__ unsigned char QTC[72][3] = {
  {15,0,64},{15,1,65},{15,2,66},{15,3,67},{15,4,68},{15,5,69},{15,6,70},{15,7,71},
  {14,0,56},{14,1,57},{14,2,58},{14,3,59},{14,4,60},{14,5,61},{14,6,62},{14,7,63},
  {13,0,49},{13,1,50},{13,2,51},{13,3,52},{13,4,53},{13,5,54},{13,6,55},
  {12,0,42},{12,1,43},{12,2,44},{12,3,45},{12,4,46},{12,5,47},{12,6,48},
  {11,0,36},{11,1,37},{11,2,38},{11,3,39},{11,4,40},{11,5,41},
  {10,0,30},{10,1,31},{10,2,32},{10,3,33},{10,4,34},{10,5,35},
  {9,0,25},{9,1,26},{9,2,27},{9,3,28},{9,4,29},
  {8,0,20},{8,1,21},{8,2,22},{8,3,23},{8,4,24},
  {7,0,16},{7,1,17},{7,2,18},{7,3,19},
  {6,0,12},{6,1,13},{6,2,14},{6,3,15},
  {5,0,9},{5,1,10},{5,2,11},
  {4,0,6},{4,1,7},{4,2,8},
  {3,0,4},{3,1,5},
  {2,0,2},{2,1,3},
  {1,0,1},
  {0,0,0}
};
__device__ __constant__ unsigned char OFFT[16] =
  {0,1,2,4,6,9,12,16,20,25,30,36,42,49,56,64};

// ---------------- fused prep: conv x / w_attn / w_proj + tables + knmax ----------------
__device__ __forceinline__ void conv_one(
    const float* __restrict__ in, u16* __restrict__ out, int c)
{
  int row = c >> 7, cc = c & 127;           // 128 chunks per 1024-elem row
  int ks = cc >> 3, ch = cc & 7;
  const float4* src = (const float4*)(in + ((size_t)row << 10) + (cc << 3));
  float4 a = src[0], b = src[1];
  s16x8 o;
  o[0] = (short)f2bf(a.x); o[1] = (short)f2bf(a.y);
  o[2] = (short)f2bf(a.z); o[3] = (short)f2bf(a.w);
  o[4] = (short)f2bf(b.x); o[5] = (short)f2bf(b.y);
  o[6] = (short)f2bf(b.z); o[7] = (short)f2bf(b.w);
  *(s16x8*)(out + ((size_t)row << 10) + (ks << 6) + ((ch ^ (row & 7)) << 3)) = o;
}

__global__ __launch_bounds__(256) void prep_all(
    const float* __restrict__ x, const float* __restrict__ w_attn,
    const float* __restrict__ w_proj, const float* __restrict__ delta,
    u16* __restrict__ xb, u16* __restrict__ wab, u16* __restrict__ wpb,
    float* __restrict__ postab, float* __restrict__ dtab, int* __restrict__ knmaxI)
{
  const int gid = blockIdx.x * 256 + threadIdx.x;
  if (gid < 32) knmaxI[gid] = 0;
  if (gid < 524288) {                        // x: 4096*128 chunks
    conv_one(x, xb, gid);
  } else if (gid < 917504) {                 // w_attn: 3072*128
    conv_one(w_attn, wab, gid - 524288);
  } else if (gid < 1048576) {                // w_proj: 1024*128
    conv_one(w_proj, wpb, gid - 917504);
  } else {                                   // tables: T_*64
    int idx = gid - 1048576;
    int t = idx >> 6, d = idx & 63;
    float invf = powf(10000.f, -(float)d * (1.0f / 64.0f));
    float ang = (float)t * invf;
    float sp, cp;
    sincosf(ang, &sp, &cp);
    postab[idx * 2 + 0] = cp;
    postab[idx * 2 + 1] = sp;
    if (idx < HN_ * 64) {
      float dl = delta[idx];
      dl = fminf(fmaxf(dl, -6.2831853071795865f), 0.f);
      float sd, cd;
      sincosf(dl, &sd, &cd);
      dtab[idx * 2 + 0] = cd;
      dtab[idx * 2 + 1] = sd;
    }
  }
}

// ---------------- bf16 MFMA GEMM (NT), 128x128, 4 waves ----------------
// 1-D grid, XCD-chunked block remap: xcd = bid&7 gets contiguous by-range.
template<int OUTK>
__global__ __launch_bounds__(256) void gemm_nt_mfma(
    const u16* __restrict__ A, const u16* __restrict__ Bw,
    void* __restrict__ Cout, int N, int BX, int NPX)
{
  __shared__ u16 As[128 * 64];
  __shared__ u16 Bs[128 * 64];
  const int tid = threadIdx.x;
  const int w = tid >> 6, l = tid & 63, g = l >> 4;
  const int bid = blockIdx.x;
  const int f = (bid & 7) * NPX + (bid >> 3);   // bijective XCD-chunked remap
  const int bm = (f / BX) * 128, bn = (f % BX) * 128;
  const int wr = w >> 1, wc = w & 1;
  const int K = 1024;

  const f32x4 zero = {0.f, 0.f, 0.f, 0.f};
  f32x4 acc[4][4];
  #pragma unroll
  for (int mt = 0; mt < 4; ++mt)
    #pragma unroll
    for (int nt = 0; nt < 4; ++nt) acc[mt][nt] = zero;

  for (int kt = 0; kt < K; kt += 64) {
    __syncthreads();
    #pragma unroll
    for (int j = 0; j < 4; ++j) {
      int cid = (j * 4 + w) * 64 + l;           // chunk 0..1023
      int row = cid >> 3, cc = cid & 7;
      gload16(As + ((j * 4 + w) << 9), A  + (size_t)(bm + row) * K + kt + cc * 8);
      gload16(Bs + ((j * 4 + w) << 9), Bw + (size_t)(bn + row) * K + kt + cc * 8);
    }
    __syncthreads();
    #pragma unroll
    for (int ks = 0; ks < 2; ++ks) {
      s16x8 af[4], bfr[4];
      #pragma unroll
      for (int mt = 0; mt < 4; ++mt) {
        int rr = wr * 64 + mt * 16 + (l & 15);
        af[mt] = *(const s16x8*)(As + rr * 64 + (((ks * 4 + g) ^ (rr & 7)) << 3));
      }
      #pragma unroll
      for (int nt = 0; nt < 4; ++nt) {
        int rr = wc * 64 + nt * 16 + (l & 15);
        bfr[nt] = *(const s16x8*)(Bs + rr * 64 + (((ks * 4 + g) ^ (rr & 7)) << 3));
      }
      #pragma unroll
      for (int mt = 0; mt < 4; ++mt)
        #pragma unroll
        for (int nt = 0; nt < 4; ++nt)
          acc[mt][nt] = mfma16(af[mt], bfr[nt], acc[mt][nt]);
    }
  }

  #pragma unroll
  for (int mt = 0; mt < 4; ++mt)
    #pragma unroll
    for (int nt = 0; nt < 4; ++nt)
      #pragma unroll
      for (int r = 0; r < 4; ++r) {
        int row = bm + wr * 64 + mt * 16 + g * 4 + r;
        int col = bn + wc * 64 + nt * 16 + (l & 15);
        if (OUTK == 0)
          ((u16*)Cout)[(size_t)row * N + col] = f2bf(acc[mt][nt][r]);
        else
          ((float*)Cout)[(size_t)row * N + col] = acc[mt][nt][r];
      }
}

// ---------------- PoPE prepass ----------------
__global__ __launch_bounds__(256) void pope_prep(
    const u16* __restrict__ qkvb, const float* __restrict__ postab,
    const float* __restrict__ dtab, u16* __restrict__ Kp, u16* __restrict__ Vtp,
    u16* __restrict__ Qp, float* __restrict__ qn, int* __restrict__ knmaxI)
{
  __shared__ u16 Vs[64][72];
  __shared__ float knsh[64];
  const int tb = blockIdx.x, h = blockIdx.y, b = blockIdx.z;
  const int t0 = tb * 64, tid = threadIdx.x;
  const int tl = tid >> 2, j = tid & 3, d0 = j * 16;
  const int t = t0 + tl;
  const size_t bh = (size_t)b * HN_ + h;
  const size_t qrow = (size_t)(b * T_ + t) * 3072 + h * 64;
  const float2* pt = (const float2*)postab + (size_t)t * 64 + d0;

  // ---- K with phases (swizzled) + k-norm ----
  float kss = 0.f;
  {
    s16x8 k0 = *(const s16x8*)(qkvb + qrow + 1024 + d0);
    s16x8 k1 = *(const s16x8*)(qkvb + qrow + 1024 + d0 + 8);
    const float2* dt = (const float2*)dtab + h * 64 + d0;
    s16x8 r0, r1, i0, i1;
    #pragma unroll
    for (int i = 0; i < 8; ++i) {
      float mu = softplus_f(bf2f((u16)k0[i]));
      kss += mu * mu;
      float2 cs = pt[i]; float2 dc = dt[i];
      r0[i] = (short)f2bf(mu * (cs.x * dc.x - cs.y * dc.y));
      i0[i] = (short)f2bf(mu * (cs.y * dc.x + cs.x * dc.y));
    }
    #pragma unroll
    for (int i = 0; i < 8; ++i) {
      float mu = softplus_f(bf2f((u16)k1[i]));
      kss += mu * mu;
      float2 cs = pt[8 + i]; float2 dc = dt[8 + i];
      r1[i] = (short)f2bf(mu * (cs.x * dc.x - cs.y * dc.y));
      i1[i] = (short)f2bf(mu * (cs.y * dc.x + cs.x * dc.y));
    }
    u16* Krow = Kp + (bh * T_ + t) * 128;
    int sw = t & 7;
    int c0 = d0 >> 3;
    *(s16x8*)(Krow + ((c0 ^ sw) << 3))       = r0;
    *(s16x8*)(Krow + (((c0 + 1) ^ sw) << 3)) = r1;
    *(s16x8*)(Krow + (((c0 + 8) ^ sw) << 3)) = i0;
    *(s16x8*)(Krow + (((c0 + 9) ^ sw) << 3)) = i1;
  }
  kss += __shfl_xor(kss, 1);
  kss += __shfl_xor(kss, 2);
  if (j == 0) knsh[tl] = kss;

  // ---- Q with pos phase (plain) + q-norm ----
  float qss = 0.f;
  {
    s16x8 q0 = *(const s16x8*)(qkvb + qrow + d0);
    s16x8 q1 = *(const s16x8*)(qkvb + qrow + d0 + 8);
    s16x8 r0, r1, i0, i1;
    #pragma unroll
    for (int i = 0; i < 8; ++i) {
      float mu = softplus_f(bf2f((u16)q0[i]));
      qss += mu * mu;
      float2 cs = pt[i];
      r0[i] = (short)f2bf(mu * cs.x);
      i0[i] = (short)f2bf(mu * cs.y);
    }
    #pragma unroll
    for (int i = 0; i < 8; ++i) {
      float mu = softplus_f(bf2f((u16)q1[i]));
      qss += mu * mu;
      float2 cs = pt[8 + i];
      r1[i] = (short)f2bf(mu * cs.x);
      i1[i] = (short)f2bf(mu * cs.y);
    }
    u16* Qrow = Qp + (bh * T_ + t) * 128;
    *(s16x8*)(Qrow + d0)          = r0;
    *(s16x8*)(Qrow + d0 + 8)      = r1;
    *(s16x8*)(Qrow + 64 + d0)     = i0;
    *(s16x8*)(Qrow + 64 + d0 + 8) = i1;
  }
  qss += __shfl_xor(qss, 1);
  qss += __shfl_xor(qss, 2);
  if (j == 0) qn[bh * T_ + t] = sqrtf(qss);

  // ---- V transpose via LDS (swizzled) ----
  {
    s16x8 v0 = *(const s16x8*)(qkvb + qrow + 2048 + d0);
    s16x8 v1 = *(const s16x8*)(qkvb + qrow + 2048 + d0 + 8);
    *(s16x8*)(&Vs[tl][d0])     = v0;
    *(s16x8*)(&Vs[tl][d0 + 8]) = v1;
  }
  __syncthreads();
  if (tid == 0) {
    float mx = 0.f;
    #pragma unroll
    for (int i = 0; i < 64; ++i) mx = fmaxf(mx, knsh[i]);
    atomicMax(knmaxI + bh, __float_as_int(sqrtf(mx)));
  }
  {
    const int d = tid >> 2, jj = tid & 3, ts0 = jj * 16;
    u16* Vrow = Vtp + (bh * 64 + d) * T_;
    int swd = d & 7;
    s16x8 o0, o1;
    #pragma unroll
    for (int i = 0; i < 8; ++i) {
      o0[i] = (short)Vs[ts0 + i][d];
      o1[i] = (short)Vs[ts0 + 8 + i][d];
    }
    int cc0 = ts0 >> 3;
    *(s16x8*)(Vrow + t0 + ((cc0 ^ swd) << 3))       = o0;
    *(s16x8*)(Vrow + t0 + (((cc0 + 1) ^ swd) << 3)) = o1;
  }
}

// ---------------- split flash attention, 32x32, fixed-m, 2-deep pipeline ----------------
__global__ __launch_bounds__(256) void attn_split(
    const u16* __restrict__ Qp, const u16* __restrict__ Kp,
    const u16* __restrict__ Vtp, const float* __restrict__ qn,
    const int* __restrict__ knmaxI, u16* __restrict__ po, float* __restrict__ pl)
{
  const int xcd = (int)blockIdx.x & 7;
  const int idx = (int)blockIdx.x >> 3;      // 0..287
  const int bh = xcd + 8 * (idx / 72);
  const int w72 = idx % 72;
  const int qt = QTC[w72][0], c = QTC[w72][1];
  const int slot = bh * 72 + QTC[w72][2];

  __shared__ u16 smem[2][12288];             // 2 x (K 16KB + Vt 8KB) = 48 KB
  const int tid = threadIdx.x, w = tid >> 6, l = tid & 63;
  const int hi = l >> 5, ln = l & 31;

  const int kbeg = c * 256;
  const int kend0 = (qt + 1) * 128;
  const int kend = kend0 < kbeg + 256 ? kend0 : kbeg + 256;
  const int ntile = (kend - kbeg) >> 6;      // 2 or 4

  const float LS = 0.125f * 1.4426950408889634f;   // scale * log2(e)
  const u16* Kpb = Kp + (size_t)bh * T_ * 128;
  const u16* Vtb = Vtp + (size_t)bh * 64 * T_;

  auto STAGE = [&](int buf, int s0) {
    u16* Kd = smem[buf];
    u16* Vd = smem[buf] + 8192;
    #pragma unroll
    for (int jj = 0; jj < 4; ++jj) {
      int cid = (jj * 4 + w) * 64 + l;         // 0..1023
      int row = cid >> 4, cc = cid & 15;
      gload16(Kd + ((jj * 4 + w) << 9), Kpb + (size_t)(s0 + row) * 128 + cc * 8);
    }
    #pragma unroll
    for (int jj = 0; jj < 2; ++jj) {
      int cid = (jj * 4 + w) * 64 + l;         // 0..511
      int row = cid >> 3, cc = cid & 7;
      gload16(Vd + ((jj * 4 + w) << 9), Vtb + (size_t)row * T_ + s0 + cc * 8);
    }
  };

  STAGE(0, kbeg);                              // tile 0 in flight first

  // ---- Q fragments + fixed m (loads overlap with stage0) ----
  const int q = qt * 128 + w * 32 + ln;
  s16x8 qf[8];
  {
    const u16* qrp = Qp + ((size_t)bh * T_ + q) * 128;
    #pragma unroll
    for (int ks = 0; ks < 8; ++ks)
      qf[ks] = *(const s16x8*)(qrp + ks * 16 + hi * 8);
  }
  const float knm = __int_as_float(knmaxI[bh]);
  const float m = LS * qn[(size_t)bh * T_ + q] * knm;

  STAGE(1, kbeg + 64);                         // tile 1 in flight

  const f32x16 zero16 = {0.f,0.f,0.f,0.f,0.f,0.f,0.f,0.f,
                         0.f,0.f,0.f,0.f,0.f,0.f,0.f,0.f};
  f32x16 o0 = zero16, o1 = zero16;
  float lsum = 0.f;
  const int qminw = qt * 128 + w * 32;

  for (int ti = 0; ti < ntile; ++ti) {
    const int s0 = kbeg + ti * 64;
    if (ti + 1 < ntile)
      asm volatile("s_waitcnt vmcnt(6)" ::: "memory");   // tile-ti (+Q) done
    else
      asm volatile("s_waitcnt vmcnt(0)" ::: "memory");
    __builtin_amdgcn_s_barrier();              // all waves: tile ready
    __builtin_amdgcn_sched_barrier(0);

    const u16* Ks  = smem[ti & 1];
    const u16* Vts = smem[ti & 1] + 8192;

    if (s0 <= qminw + 31) {
      const bool needmask = (s0 + 63) > qminw;

      // ---- QK^T (swapped): C[s][q] ----
      f32x16 sacc0 = zero16, sacc1 = zero16;
      __builtin_amdgcn_s_setprio(1);
      #pragma unroll
      for (int ks = 0; ks < 8; ++ks) {
        int r0_ = ln, r1_ = 32 + ln;
        s16x8 kf0 = *(const s16x8*)(Ks + r0_ * 128 + (((2 * ks + hi) ^ (r0_ & 7)) << 3));
        s16x8 kf1 = *(const s16x8*)(Ks + r1_ * 128 + (((2 * ks + hi) ^ (r1_ & 7)) << 3));
        sacc0 = mfma32(kf0, qf[ks], sacc0);
        sacc1 = mfma32(kf1, qf[ks], sacc1);
      }
      __builtin_amdgcn_s_setprio(0);

      // ---- mask + p = exp2(sc*LS - m) IN PLACE ----
      if (needmask) {
        #pragma unroll
        for (int jj = 0; jj < 16; ++jj) {
          int sg = s0 + (jj & 3) + 8 * (jj >> 2) + 4 * hi;
          if (sg > q)      sacc0[jj] = -3e38f;
          if (sg + 32 > q) sacc1[jj] = -3e38f;
        }
      }
      float rs = 0.f;
      #pragma unroll
      for (int jj = 0; jj < 16; ++jj) {
        float p0 = exp2f(fmaf(sacc0[jj], LS, -m));
        float p1 = exp2f(fmaf(sacc1[jj], LS, -m));
        sacc0[jj] = p0; sacc1[jj] = p1;
        rs += p0 + p1;
      }
      lsum += rs;

      // ---- P -> bf16 A-frags via cvt_pk + permlane32_swap ----
      s16x8 pa[4];
      #pragma unroll
      for (int ks = 0; ks < 4; ++ks) {
        const int bb = (ks & 1) * 8;
        unsigned a0, a1, b0v, b1v;
        if (ks < 2) {
          a0  = cvtpk(sacc0[bb + 0], sacc0[bb + 1]);
          a1  = cvtpk(sacc0[bb + 2], sacc0[bb + 3]);
          b0v = cvtpk(sacc0[bb + 4], sacc0[bb + 5]);
          b1v = cvtpk(sacc0[bb + 6], sacc0[bb + 7]);
        } else {
          a0  = cvtpk(sacc1[bb + 0], sacc1[bb + 1]);
          a1  = cvtpk(sacc1[bb + 2], sacc1[bb + 3]);
          b0v = cvtpk(sacc1[bb + 4], sacc1[bb + 5]);
          b1v = cvtpk(sacc1[bb + 6], sacc1[bb + 7]);
        }
        asm("v_permlane32_swap_b32 %0, %1" : "+v"(a0), "+v"(b0v));
        asm("v_permlane32_swap_b32 %0, %1" : "+v"(a1), "+v"(b1v));
        union { unsigned u[4]; s16x8 v; } pu;
        pu.u[0] = a0; pu.u[1] = a1; pu.u[2] = b0v; pu.u[3] = b1v;
        pa[ks] = pu.v;
      }

      // ---- PV: o[q][d] += P x V ----
      __builtin_amdgcn_s_setprio(1);
      #pragma unroll
      for (int ks = 0; ks < 4; ++ks) {
        int rd0 = ln, rd1 = 32 + ln;
        s16x8 vb0 = *(const s16x8*)(Vts + rd0 * 64 + (((2 * ks + hi) ^ (rd0 & 7)) << 3));
        s16x8 vb1 = *(const s16x8*)(Vts + rd1 * 64 + (((2 * ks + hi) ^ (rd1 & 7)) << 3));
        o0 = mfma32(pa[ks], vb0, o0);
        o1 = mfma32(pa[ks], vb1, o1);
      }
      __builtin_amdgcn_s_setprio(0);
    }
    __builtin_amdgcn_s_barrier();              // all waves done reading buf
    if (ti + 2 < ntile) STAGE(ti & 1, s0 + 128);
  }

  // ---- epilogue: write partials (o bf16, l f32) ----
  lsum += __shfl_xor(lsum, 32);
  u16* pob = po + (size_t)slot * 8192;
  #pragma unroll
  for (int jj = 0; jj < 16; ++jj) {
    int row = w * 32 + 4 * hi + (jj & 3) + 8 * (jj >> 2);
    pob[row * 64 + ln]      = f2bf(o0[jj]);
    pob[row * 64 + 32 + ln] = f2bf(o1[jj]);
  }
  if (hi == 0)
    pl[(size_t)slot * 128 + w * 32 + ln] = lsum;
}

// ---------------- combine partials -> yb (XCD-pinned, 1024 blocks) ----------------
__global__ __launch_bounds__(256) void attn_combine(
    const u16* __restrict__ po, const float* __restrict__ pl,
    u16* __restrict__ yb)
{
  const int xcd = (int)blockIdx.x & 7;
  const int i = (int)blockIdx.x >> 3;        // 0..127
  const int bh = xcd + 8 * (i & 3);          // same XCD as the writers of bh
  const int qt = 15 - ((i >> 2) & 15);       // heavy first
  const int half = i >> 6;                   // 0..1: row halves
  const int b = bh >> 4, h = bh & 15;
  const int nch = (qt + 2) >> 1;             // ceil((qt+1)/2)
  const int base = bh * 72 + OFFT[qt];
  const int t = threadIdx.x;
  const int row = half * 64 + (t >> 2);      // 64 rows per block
  const int d0 = (t & 3) * 16;

  float acc[16];
  #pragma unroll
  for (int i2 = 0; i2 < 16; ++i2) acc[i2] = 0.f;
  float ls = 0.f;
  for (int c = 0; c < nch; ++c) {
    const u16* pr = po + (size_t)(base + c) * 8192 + row * 64 + d0;
    #pragma unroll
    for (int v = 0; v < 2; ++v) {
      s16x8 x = *(const s16x8*)(pr + v * 8);
      #pragma unroll
      for (int i2 = 0; i2 < 8; ++i2) acc[v * 8 + i2] += bf2f((u16)x[i2]);
    }
    ls += pl[(size_t)(base + c) * 128 + row];
  }
  float inv = 1.f / ls;
  int qrow = qt * 128 + row;
  size_t rb = (size_t)(b * T_ + qrow) * 1024 + h * 64;
  #pragma unroll
  for (int v = 0; v < 2; ++v) {
    int ch = ((d0 >> 3) + v) ^ (qrow & 7);
    s16x8 o;
    #pragma unroll
    for (int i2 = 0; i2 < 8; ++i2) o[i2] = (short)f2bf(acc[v * 8 + i2] * inv);
    *(s16x8*)(yb + rb + (ch << 3)) = o;
  }
}

// ---------------------------------------------------------------------------
extern "C" void kernel_launch(void* const* d_in, const int* in_sizes, int n_in,
                              void* d_out, int out_size, void* d_ws, size_t ws_size,
                              hipStream_t stream)
{
  const float* x      = (const float*)d_in[0];   // (B,T,C)
  const float* w_attn = (const float*)d_in[1];   // (3C,C)
  const float* w_proj = (const float*)d_in[2];   // (C,C)
  const float* delta  = (const float*)d_in[3];   // (H,D)
  float* out = (float*)d_out;

  char* p = (char*)d_ws;
  // --- phase-1 region (dead after pope_prep) -> reused as po by attn ---
  u16* qkvb   = (u16*)p;                                        // 24 MB
  u16* xb     = (u16*)(p + (size_t)4096 * 3072 * 2);            //  8 MB
  u16* wab    = (u16*)(p + (size_t)4096 * 3072 * 2 + (size_t)4096 * 1024 * 2); // 6 MB
  u16* po     = (u16*)p;        // 2304 slots * 16KB = 36.9 MB, aliases the above
  p += (size_t)(4096 * 3072 + 4096 * 1024 + 3072 * 1024) * 2;   // 38.8 MB
  // --- persistent region ---
  u16* wpb    = (u16*)p;  p += (size_t)1024 * 1024 * 2;
  u16* yb     = (u16*)p;  p += (size_t)4096 * 1024 * 2;
  u16* Kp     = (u16*)p;  p += (size_t)B_ * HN_ * T_ * 128 * 2;
  u16* Vtp    = (u16*)p;  p += (size_t)B_ * HN_ * 64 * T_ * 2;
  u16* Qp     = (u16*)p;  p += (size_t)B_ * HN_ * T_ * 128 * 2;
  float* postab = (float*)p; p += (size_t)T_ * 64 * 2 * 4;
  float* dtab   = (float*)p; p += (size_t)HN_ * 64 * 2 * 4;
  float* qn     = (float*)p; p += (size_t)B_ * HN_ * T_ * 4;
  float* pl     = (float*)p; p += (size_t)2304 * 128 * 4;
  int*   knmaxI = (int*)p;   p += 32 * 4;

  // fused prep: conv x/w_attn/w_proj + trig tables + knmax zero (1 launch)
  prep_all<<<dim3((1048576 + T_ * 64) / 256), 256, 0, stream>>>(
      x, w_attn, w_proj, delta, xb, wab, wpb, postab, dtab, knmaxI);

  // qkv GEMM: 768 blocks, XCD-chunked (BX=24 bn-blocks, 96 blocks/XCD)
  gemm_nt_mfma<0><<<dim3(768), 256, 0, stream>>>(xb, wab, qkvb, 3072, 24, 96);
  pope_prep<<<dim3(T_ / 64, HN_, B_), 256, 0, stream>>>(qkvb, postab, dtab, Kp, Vtp,
                                                        Qp, qn, knmaxI);
  attn_split<<<dim3(2304), 256, 0, stream>>>(Qp, Kp, Vtp, qn, knmaxI, po, pl);
  attn_combine<<<dim3(1024), 256, 0, stream>>>(po, pl, yb);
  // proj GEMM: 256 blocks, XCD-chunked (BX=8 bn-blocks, 32 blocks/XCD)
  gemm_nt_mfma<1><<<dim3(256), 256, 0, stream>>>(yb, wpb, out, 1024, 8, 32);
}